// Round 6
// baseline (173.128 us; speedup 1.0000x reference)
//
#include <hip/hip_runtime.h>

#define SQ 2048
#define DH 64
#define NH 12
#define NBH 48          // B*H
#define QTILE 128       // q rows per block (32 per wave)
#define KTILE 64        // keys per iteration
#define NITER (SQ / KTILE)
#define NQT (SQ / QTILE)   // 16 q-tiles -> 768 blocks = 3 blocks/CU

// LDS arena: 3 K slots (0,8192,16384) + 3 V slots (24576+{0,8192,16384}) = 48 KB
#define VARENA 24576

typedef short short8 __attribute__((ext_vector_type(8)));
typedef float f32x2  __attribute__((ext_vector_type(2)));
typedef float f32x4  __attribute__((ext_vector_type(4)));
typedef float f32x16 __attribute__((ext_vector_type(16)));
typedef int   i32x2 __attribute__((ext_vector_type(2)));
typedef int   i32x4 __attribute__((ext_vector_type(4)));

#define MFMA32(a, b, c) __builtin_amdgcn_mfma_f32_32x32x16_bf16(a, b, c, 0, 0, 0)

typedef __attribute__((address_space(1))) const void* gas_ptr;
typedef __attribute__((address_space(3))) void* las_ptr;

__device__ __forceinline__ void load_lds16(const void* g, void* l) {
    // 16B/lane direct global->LDS DMA; LDS dest = wave-uniform base + lane*16
    __builtin_amdgcn_global_load_lds((gas_ptr)g, (las_ptr)l, 16, 0, 0);
}

// two fp32 -> packed bf16x2 (low = a, high = b), RTNE
#if defined(__has_builtin) && __has_builtin(__builtin_amdgcn_cvt_pk_bf16_f32)
typedef __bf16 bf16x2_t __attribute__((ext_vector_type(2)));
__device__ __forceinline__ unsigned pk2bf(float a, float b) {
    bf16x2_t v = __builtin_amdgcn_cvt_pk_bf16_f32(a, b);
    union { bf16x2_t v; unsigned u; } c; c.v = v; return c.u;
}
#else
__device__ __forceinline__ unsigned pk2bf(float a, float b) {
    union { float f; unsigned u; } x, y; x.f = a; y.f = b;
    unsigned ra = x.u + 0x7FFFu + ((x.u >> 16) & 1u);
    unsigned rb = y.u + 0x7FFFu + ((y.u >> 16) & 1u);
    return (ra >> 16) | (rb & 0xFFFF0000u);
}
#endif

#ifdef __has_builtin
#if __has_builtin(__builtin_amdgcn_permlane32_swap)
#define HAVE_PLSWAP 1
#else
#define HAVE_PLSWAP 0
#endif
#else
#define HAVE_PLSWAP 0
#endif

// ------- fused pre-pass: K fp32->bf16 (blocks 0..3071)  |  V transpose (rest) -------
#define KCONV_BLOCKS (NBH * SQ * DH / 8 / 256)   // 3072
__global__ __launch_bounds__(256)
void prepass(const float* __restrict__ K, short* __restrict__ Kb,
             const float* __restrict__ V, short* __restrict__ Vt) {
    __shared__ float Ls[64][68];   // transpose staging (+4 pad)
    if (blockIdx.x < KCONV_BLOCKS) {
        const size_t i = (size_t)(blockIdx.x * 256 + threadIdx.x) * 8;
        f32x4 a = *(const f32x4*)&K[i];
        f32x4 b = *(const f32x4*)&K[i + 4];
        unsigned o[4] = { pk2bf(a[0], a[1]), pk2bf(a[2], a[3]),
                          pk2bf(b[0], b[1]), pk2bf(b[2], b[3]) };
        *(i32x4*)&Kb[i] = *(i32x4*)o;
        return;
    }
    const int bx = blockIdx.x - KCONV_BLOCKS;
    const int st = bx & 31;       // s tile
    const int bh = bx >> 5;
    const int b = bh / NH, h = bh % NH;
    const int s0 = st * 64;
    const float* src = V + ((size_t)b * SQ * NH + (size_t)h) * DH;
    const int dg = threadIdx.x & 15;   // d = 4*dg
    const int sl = threadIdx.x >> 4;   // 0..15
    #pragma unroll
    for (int p = 0; p < 4; ++p) {
        const int row = p * 16 + sl;
        *(f32x4*)&Ls[row][dg * 4] =
            *(const f32x4*)&src[(size_t)(s0 + row) * (NH * DH) + dg * 4];
    }
    __syncthreads();
    const int dr = threadIdx.x >> 2;        // d row 0..63
    const int sc = (threadIdx.x & 3) * 16;  // s chunk
    unsigned out[8];
    #pragma unroll
    for (int jj = 0; jj < 8; ++jj)
        out[jj] = pk2bf(Ls[sc + 2 * jj][dr], Ls[sc + 2 * jj + 1][dr]);
    short* dst = Vt + (size_t)bh * DH * SQ + (size_t)dr * SQ + s0 + sc;
    *(i32x4*)(dst)     = *(i32x4*)&out[0];
    *(i32x4*)(dst + 8) = *(i32x4*)&out[4];
}

// ------------- main fused attention (32x32x16 MFMA, counted-vmcnt pipeline) -------------
// r5 post-mortem: MFMA(21us) + VALU(38us) + LDS-read(31us) ~= dur(84us) -> pipes run
// SEQUENTIALLY. Cause: __syncthreads per tile = s_waitcnt vmcnt(0)+barrier -> all 12
// waves/CU drain ALL DMAs and re-enter in lockstep. Fix (T3/T4): 3-deep K/V rings so a
// DMA issued at tile t is first read at tile t+2 (2 bodies of flight), and the per-tile
// sync is {s_waitcnt vmcnt(4) [retire only the 2-old batch; newest 4 loads FLY ACROSS
// the barrier]; raw s_barrier}. Issue count is uniform (4 loads/tile; tail indices
// clamped into dead slots) so the count is constant. vmcnt(0) once before exit.
__global__ __launch_bounds__(256, 3)
void attn_fused_kernel(const float* __restrict__ Q,
                       const short* __restrict__ Kb,   // bf16 [BH][S][D]
                       const short* __restrict__ Vtg,  // bf16 [BH][D][S]
                       float* __restrict__ O) {
    // K slot i at i*8192 (halves +0 rows0-31, +4096 rows32-63)
    // V slot i at VARENA+i*8192 (halves +0 d0-31, +4096 d32-63)
    // XOR chunk swizzle (chunk c of row r at c^(r&7)); unpadded 128B rows.
    __shared__ __align__(16) char L[49152];

    const int tid  = threadIdx.x;
    const int lane = tid & 63;
    const int w    = tid >> 6;
    const int m31  = lane & 31;     // MFMA row/col index
    const int hl   = lane >> 5;     // half-wave 0/1
    const int l7   = lane & 7;

    // ---- XCD-locality swizzle: dispatch round-robins XCDs by (bx & 7).
    const int bx  = blockIdx.x;
    const int xcd = bx & 7;
    const int i96 = bx >> 3;          // 0..95
    const int bh  = xcd * 6 + (i96 % 6);
    const int qt  = i96 / 6;          // 0..15
    const int q0 = qt * QTILE;

    const float* Qb  = Q   + (size_t)bh * SQ * DH;
    const short* Kbh = Kb  + (size_t)bh * SQ * DH;
    const short* Vbh = Vtg + (size_t)bh * DH * SQ;
    float*       Ob  = O   + (size_t)bh * SQ * DH;

    // scale folded into Q, exp as exp2: 1/sqrt(768) * log2(e)
    const float qscale = 0.03608439182435161f * 1.4426950408889634f;

    // ---- Q fragments (B operand: n=m31 -> q row, k=16*s+8*hl+j) ----
    short8 qf[4];
    {
        const int qrow = q0 + 32 * w + m31;
        #pragma unroll
        for (int s = 0; s < 4; ++s) {
            const float* src = Qb + (size_t)qrow * DH + 16 * s + 8 * hl;
            f32x4 qa = *(const f32x4*)src;
            f32x4 qb = *(const f32x4*)(src + 4);
            union { unsigned u[4]; short8 v; } f;
            f.u[0] = pk2bf(qa[0] * qscale, qa[1] * qscale);
            f.u[1] = pk2bf(qa[2] * qscale, qa[3] * qscale);
            f.u[2] = pk2bf(qb[0] * qscale, qb[1] * qscale);
            f.u[3] = pk2bf(qb[2] * qscale, qb[3] * qscale);
            qf[s] = f.v;
        }
    }

    // ---- staging source pointers (lane-constant swizzle) ----
    const int gk = (lane & 7) ^ (lane >> 3);
    const int rr = w * 8 + (lane >> 3);
    const short* kg0 = Kbh + (size_t)rr * DH + gk * 8;
    const short* kg1 = kg0 + 32 * DH;
    const short* vg0 = Vbh + (size_t)rr * SQ + gk * 8;
    const short* vg1 = vg0 + 32 * SQ;
    const int wslot = w * 1024;   // scalar

    // ---- loop-invariant per-lane LDS frag addresses (bytes) ----
    int aoff[4];
    #pragma unroll
    for (int s = 0; s < 4; ++s) aoff[s] = m31 * 128 + (((2 * s + hl) ^ l7) * 16);

    // ---- pipeline state: captured named vars / constant-indexed arrays only ----
    f32x16 o0 = {}, o1 = {};     // output accumulators
    f32x16 sn0, sn1;             // current tile's score halves (die at their sm)
    short8 pfc[4];               // carried packed P fragments
    f32x2 lpa = {0.f, 0.f};      // row-sum accumulators (2 independent chains)
    f32x2 lpb = {0.f, 0.f};

    // issue K tile t into K slot offset ks (2 loads/wave via DMA)
    auto issueK = [&](int ks, int t) {
        const short* p0 = kg0 + (size_t)t * (KTILE * DH);
        const short* p1 = kg1 + (size_t)t * (KTILE * DH);
        load_lds16(p0, L + ks + wslot);
        load_lds16(p1, L + ks + 4096 + wslot);
    };
    // issue V tile t into V slot offset vs (2 loads/wave)
    auto issueV = [&](int vs, int t) {
        const short* p0 = vg0 + (size_t)t * KTILE;
        const short* p1 = vg1 + (size_t)t * KTILE;
        load_lds16(p0, L + VARENA + vs + wslot);
        load_lds16(p1, L + VARENA + vs + 4096 + wslot);
    };

    // QK^T from K slot ks -> sn0, sn1
    auto qk = [&](int ks) {
        f32x16 a0 = {}, a1 = {};
        #pragma unroll
        for (int s = 0; s < 4; ++s) {
            short8 ka0 = *(const short8*)(L + ks + aoff[s]);
            short8 ka1 = *(const short8*)(L + ks + 4096 + aoff[s]);
            a0 = MFMA32(ka0, qf[s], a0);
            a1 = MFMA32(ka1, qf[s], a1);
        }
        sn0 = a0; sn1 = a1;
    };

    // exp + in-register C->A relayout; consumes one score half into dst[0..1]
    auto softmax_pack = [&](const f32x16& sv, short8* dst) {
        #pragma unroll
        for (int wd = 0; wd < 2; ++wd) {
            float p[8];
            #pragma unroll
            for (int j = 0; j < 8; ++j)
                p[j] = __builtin_amdgcn_exp2f(sv[8 * wd + j]);
            // row-sum via packed v_pk_add_f32, two independent accumulator chains
            f32x2 s01 = {p[0], p[1]}, s23 = {p[2], p[3]};
            f32x2 s45 = {p[4], p[5]}, s67 = {p[6], p[7]};
            lpa += (s01 + s23);
            lpb += (s45 + s67);
            unsigned a0 = pk2bf(p[0], p[1]);   // kk 4hl+{0,1}
            unsigned a1 = pk2bf(p[2], p[3]);   // kk 4hl+{2,3}
            unsigned b0 = pk2bf(p[4], p[5]);   // kk 8+4hl+{0,1}
            unsigned b1 = pk2bf(p[6], p[7]);   // kk 8+4hl+{2,3}
            union { unsigned u[4]; short8 v; } fr;
#if HAVE_PLSWAP
            // r.x = {lo: a[0:31]  | hi: b[0:31]}  = A-frag word0
            // r.y = {lo: a[32:63] | hi: b[32:63]} = A-frag word2
            i32x2 r0 = __builtin_amdgcn_permlane32_swap((int)a0, (int)b0, false, false);
            i32x2 r1 = __builtin_amdgcn_permlane32_swap((int)a1, (int)b1, false, false);
            fr.u[0] = (unsigned)r0.x;
            fr.u[1] = (unsigned)r1.x;
            fr.u[2] = (unsigned)r0.y;
            fr.u[3] = (unsigned)r1.y;
#else
            unsigned r0 = (unsigned)__shfl_xor((int)(hl ? a0 : b0), 32, 64);
            unsigned r1 = (unsigned)__shfl_xor((int)(hl ? a1 : b1), 32, 64);
            fr.u[0] = hl ? r0 : a0;
            fr.u[1] = hl ? r1 : a1;
            fr.u[2] = hl ? b0 : r0;
            fr.u[3] = hl ? b1 : r1;
#endif
            dst[wd] = fr.v;
        }
    };

    // PV accumulate from V slot vs with carried pfc
    auto pv = [&](int vs) {
        #pragma unroll
        for (int s = 0; s < 4; ++s) {
            short8 vv0 = *(const short8*)(L + VARENA + vs + aoff[s]);
            short8 vv1 = *(const short8*)(L + VARENA + vs + 4096 + aoff[s]);
            o0 = MFMA32(pfc[s], vv0, o0);
            o1 = MFMA32(pfc[s], vv1, o1);
        }
    };

    // ---- prologue: stage K0,K1,V0 ("t=-2 batch"+K0), K2,V1 ("t=-1 batch"); 10 loads ----
    issueK(0, 0); issueK(8192, 1); issueV(0, 0);
    issueK(16384, 2); issueV(8192, 1);
    asm volatile("s_waitcnt vmcnt(8)" ::: "memory");   // K0's 2 loads retired
    __builtin_amdgcn_s_barrier();
    qk(0);                                   // S(0)
    softmax_pack(sn0, &pfc[0]);
    softmax_pack(sn1, &pfc[2]);

    // ---- main loop: tile t does qk(K(t+1)), pv(V(t)), sm -> P(t+1) ----
    // Rotating slot offsets: at top of iter t, b0 = (t)%3*8192, b1 = (t+1)%3*8192,
    // b2 = (t+2)%3*8192. Writes: K(t+3)->K slot b0 (held K(t), read finished at t-1),
    // V(t+2)->V slot b2 (held V(t-1), read finished at t-1). Reads: K(t+1) from b1
    // (issued at t-2, retired by this vmcnt), V(t) from b0 (issued at t-2, retired).
    // vmcnt(4): outstanding = batches t-1 (4) + t-2 (4); retire t-2's, t-1's fly on.
    int b0 = 0, b1 = 8192, b2 = 16384;
    #pragma unroll 1
    for (int t = 0; t < NITER - 1; ++t) {
        asm volatile("s_waitcnt vmcnt(4)" ::: "memory");
        __builtin_amdgcn_s_barrier();
        // tail-clamped indices keep 4 loads/tile (dups land in dead slots, never read)
        const int tk = (t + 3 < NITER) ? (t + 3) : (NITER - 1);
        const int tv = (t + 2 < NITER) ? (t + 2) : (NITER - 1);
        issueK(b0, tk);
        issueV(b2, tv);
        qk(b1);                              // S(t+1)
        pv(b0);                              // PV(t), independent of qk -> overlaps
        softmax_pack(sn0, &pfc[0]);          // P(t+1)
        softmax_pack(sn1, &pfc[2]);
        const int tmp = b0; b0 = b1; b1 = b2; b2 = tmp;
    }

    // ---- epilogue: PV(NITER-1); V(31) was issued at t=29, retired by this vmcnt ----
    asm volatile("s_waitcnt vmcnt(4)" ::: "memory");
    __builtin_amdgcn_s_barrier();
    pv(b0);                                  // b0 = (NITER-1)%3 slot
    asm volatile("s_waitcnt vmcnt(0)" ::: "memory");   // no DMA outlives the block

    // ---- finalize: l(q=m31) = lp(lane) + lp(lane^32); invert; scatter ----
    float lp = (lpa.x + lpa.y) + (lpb.x + lpb.y);
    float v = lp;
    v += __shfl_xor(v, 32, 64);
    const float linv = 1.0f / v;

    #pragma unroll
    for (int dt = 0; dt < 2; ++dt) {
        const f32x16& o = dt ? o1 : o0;
        #pragma unroll
        for (int reg = 0; reg < 16; ++reg) {
            const int qp = (reg & 3) + 8 * (reg >> 2) + 4 * hl;
            const float rl = __shfl(linv, qp, 64);
            const int q = q0 + 32 * w + qp;
            Ob[(size_t)q * DH + 32 * dt + m31] = o[reg] * rl;
        }
    }
}

extern "C" void kernel_launch(void* const* d_in, const int* in_sizes, int n_in,
                              void* d_out, int out_size, void* d_ws, size_t ws_size,
                              hipStream_t stream) {
    const float* Q = (const float*)d_in[0];
    const float* K = (const float*)d_in[1];
    const float* V = (const float*)d_in[2];
    float* O = (float*)d_out;

    // workspace: bf16 K (12.6 MB) + bf16 V^T (12.6 MB)
    short* Kb  = (short*)d_ws;
    short* Vtg = Kb + (size_t)NBH * SQ * DH;

    prepass<<<dim3(KCONV_BLOCKS + NBH * 32), dim3(256), 0, stream>>>(K, Kb, V, Vtg);
    // 768 blocks, XCD-swizzled (head-locality in per-XCD L2); 48 KB LDS, 3 blocks/CU
    attn_fused_kernel<<<dim3(NBH * NQT), dim3(256), 0, stream>>>(Q, Kb, Vtg, O);
}